// Round 7
// baseline (31.820 us; speedup 1.0000x reference)
//
#include <hip/hip_runtime.h>

#define N 512
#define D 128

// ws layout:
//   float  XT[2][128][512]   512 KB   transposed src/tgt (planar)
//   ull    rs_bits[2][512]   8 KB     complete row-sums (double bits)
//   ull    ss_bits[2][512]   8 KB     complete row sum-of-squares
//   int    counters[2]       8 B      [0]=grid barrier, [1]=finalize ticket
// counters are zeroed each call by a hipMemsetAsync graph node (ws is
// poisoned 0xAA once and never re-poisoned; the memset makes every call,
// including the un-poisoned correctness call, see 0).

__device__ __forceinline__ double wave_reduce_add(double v) {
    #pragma unroll
    for (int off = 32; off > 0; off >>= 1)
        v += __shfl_down(v, off, 64);
    return v;
}

// Single fused kernel: 256 blocks x 512 threads (8 waves/block -> 1 block/CU,
// all blocks co-resident: grid spin-barrier cannot deadlock).
__global__ __launch_bounds__(512) void gw_all(
    const float* __restrict__ src, const float* __restrict__ tgt,
    float* __restrict__ XT,
    unsigned long long* __restrict__ rs_bits,
    unsigned long long* __restrict__ ss_bits,
    int* __restrict__ counters,
    float* __restrict__ out)
{
    const int b   = blockIdx.x;
    const int tid = threadIdx.x;
    const int m   = b >> 7;          // matrix: 0=src, 1=tgt

    const float* X   = m ? tgt : src;
    float*       XTm = XT + m * (D * N);

    __shared__ float  ld[32][17];    // padded: conflict-free both phases
    __shared__ double red[8][8];     // [wave][quantity]
    __shared__ int    islast;

    // ---------- phase 1: transpose one 16d x 32j tile ----------
    // Writes go through atomicExch -> executed at the L3 coherence point,
    // visible to all XCDs (proven by R5/R6: exchanged values read correctly
    // by other blocks with plain/volatile loads).
    {
        const int dt = (b >> 4) & 7;     // 8 d-tiles of 16
        const int jt = b & 15;           // 16 j-tiles of 32
        const int jr = tid >> 4;         // 0..31
        const int dc = tid & 15;         // 0..15
        ld[jr][dc] = X[(jt * 32 + jr) * D + dt * 16 + dc];   // coalesced 64B segs
        __syncthreads();
        const int dr = tid >> 5;         // 0..15
        const int jc = tid & 31;         // 0..31
        float old = atomicExch(&XTm[(dt * 16 + dr) * N + jt * 32 + jc], ld[jc][dr]);
        asm volatile("" :: "v"(old) : "memory");  // drain: my exchange is at L3
    }
    __syncthreads();                      // whole block's exchanges complete

    // ---------- phase 2: grid spin-barrier ----------
    if (tid == 0) {
        atomicAdd(&counters[0], 1);
        while (__hip_atomic_load(&counters[0], __ATOMIC_ACQUIRE,
                                 __HIP_MEMORY_SCOPE_AGENT) < (int)gridDim.x)
            __builtin_amdgcn_s_sleep(2);
    }
    __syncthreads();
    // XT plain loads below are safe: these lines were only ever written via
    // atomics (never cached in any L2), and kernel-begin invalidated history.

    // ---------- phase 3: distances (validated R5 math) ----------
    const int iq  = b & 127;
    const int i0  = iq * 4;
    const float* r0 = X + (i0 + 0) * D;   // wave-uniform rows -> scalar loads
    const float* r1 = X + (i0 + 1) * D;
    const float* r2 = X + (i0 + 2) * D;
    const float* r3 = X + (i0 + 3) * D;

    float a0 = 0.f, a1 = 0.f, a2 = 0.f, a3 = 0.f;
    #pragma unroll 8
    for (int d = 0; d < D; ++d) {
        float v = XTm[d * N + tid];       // coalesced: lane stride 4B
        float e;
        e = r0[d] - v; a0 += e * e;
        e = r1[d] - v; a1 += e * e;
        e = r2[d] - v; a2 += e * e;
        e = r3[d] - v; a3 += e * e;
    }

    double q[8];
    q[0] = (double)a0; q[1] = (double)a1; q[2] = (double)a2; q[3] = (double)a3;
    q[4] = (double)a0 * (double)a0;
    q[5] = (double)a1 * (double)a1;
    q[6] = (double)a2 * (double)a2;
    q[7] = (double)a3 * (double)a3;

    const int wave = tid >> 6;
    const int lane = tid & 63;
    #pragma unroll
    for (int k = 0; k < 8; ++k) {
        double v = wave_reduce_add(q[k]);
        if (lane == 0) red[wave][k] = v;
    }
    __syncthreads();

    // ---------- phase 4: publish + ticket + last-block finalize ----------
    if (tid == 0) {
        unsigned long long olds[8];
        #pragma unroll
        for (int k = 0; k < 4; ++k) {
            double rs = 0.0, ss = 0.0;
            #pragma unroll
            for (int w = 0; w < 8; ++w) { rs += red[w][k]; ss += red[w][k + 4]; }
            olds[k]     = atomicExch(&rs_bits[m * N + i0 + k],
                                     (unsigned long long)__double_as_longlong(rs));
            olds[k + 4] = atomicExch(&ss_bits[m * N + i0 + k],
                                     (unsigned long long)__double_as_longlong(ss));
        }
        asm volatile("" :: "v"(olds[0]), "v"(olds[1]), "v"(olds[2]), "v"(olds[3]),
                           "v"(olds[4]), "v"(olds[5]), "v"(olds[6]), "v"(olds[7])
                     : "memory");
        int ticket = atomicAdd(&counters[1], 1);
        islast = (ticket == (int)gridDim.x - 1);
    }
    __syncthreads();

    if (islast) {
        const int i = tid;
        volatile const unsigned long long* rsv = rs_bits;
        volatile const unsigned long long* ssv = ss_bits;
        double rs_s = __longlong_as_double((long long)rsv[0 * N + i]);
        double rs_t = __longlong_as_double((long long)rsv[1 * N + i]);
        double ss_s = __longlong_as_double((long long)ssv[0 * N + i]);
        double ss_t = __longlong_as_double((long long)ssv[1 * N + i]);

        double v = (double)N * (ss_s + ss_t) - 2.0 * rs_s * rs_t;
        v = wave_reduce_add(v);
        if (lane == 0) red[wave][0] = v;
        __syncthreads();
        if (tid == 0) {
            double total = 0.0;
            #pragma unroll
            for (int w = 0; w < 8; ++w) total += red[w][0];
            out[0] = (float)(total / ((double)N * (double)N));
        }
    }
}

extern "C" void kernel_launch(void* const* d_in, const int* in_sizes, int n_in,
                              void* d_out, int out_size, void* d_ws, size_t ws_size,
                              hipStream_t stream) {
    const float* src = (const float*)d_in[0];
    const float* tgt = (const float*)d_in[1];
    float* out = (float*)d_out;

    char* w = (char*)d_ws;
    float*              XT      = (float*)w;                                 // 512 KB
    unsigned long long* rs_bits = (unsigned long long*)(w + 2 * D * N * 4);  // 8 KB
    unsigned long long* ss_bits = (unsigned long long*)(w + 2 * D * N * 4 + 2 * N * 8);
    int*                counters = (int*)(w + 2 * D * N * 4 + 4 * N * 8);

    // graph-capturable memset node: counters must be 0 every call
    hipMemsetAsync(counters, 0, 2 * sizeof(int), stream);
    gw_all<<<dim3(256), dim3(512), 0, stream>>>(src, tgt, XT, rs_bits, ss_bits,
                                                counters, out);
}

// Round 8
// 18.904 us; speedup vs baseline: 1.6833x; 1.6833x over previous
//
#include <hip/hip_runtime.h>

#define N 512
#define D 128

// ws layout (doubles): rs[2][512] | ss[2][512]   (16 KB)
// No transpose buffer, no counters, no atomics anywhere.

__device__ __forceinline__ double wave_reduce_add(double v) {
    #pragma unroll
    for (int off = 32; off > 0; off >>= 1)
        v += __shfl_down(v, off, 64);
    return v;
}

// K1: 256 blocks x 512 threads. Block b = (m = b>>7, iq = b&127) owns rows
// i0..i0+3 of ONE matrix over the FULL j-range (thread tid = j).
// Self-stages the X plane through LDS in 4 d-chunks of 32 (transposed,
// padded stride 513 -> stage writes <=2-way banked (free), compute reads
// stride-1 conflict-free). Math identical to validated rounds: per-(i,j)
// f32 distance, all j-summation in double. Plain stores publish rs/ss.
__global__ __launch_bounds__(512) void gw_dist(
    const float* __restrict__ src, const float* __restrict__ tgt,
    double* __restrict__ rs, double* __restrict__ ss)
{
    __shared__ float  tile[32 * 513];   // 64.1 KB: one 32-d chunk, transposed
    __shared__ double red[8][8];        // [wave][quantity]

    const int b   = blockIdx.x;
    const int m   = b >> 7;
    const int iq  = b & 127;
    const int i0  = iq * 4;
    const int tid = threadIdx.x;        // j

    const float*  X  = m ? tgt : src;
    const float4* X4 = reinterpret_cast<const float4*>(X);
    const float* r0  = X + (i0 + 0) * D;   // wave-uniform rows -> scalar loads
    const float* r1  = X + (i0 + 1) * D;
    const float* r2  = X + (i0 + 2) * D;
    const float* r3  = X + (i0 + 3) * D;

    const int jhome = tid >> 3;         // staging row this thread covers (per pass)
    const int d4    = tid & 7;          // float4 slot within the 32-d chunk

    float a0 = 0.f, a1 = 0.f, a2 = 0.f, a3 = 0.f;

    for (int c = 0; c < 4; ++c) {       // d-chunk: dims [c*32, c*32+32)
        // ---- stage: 8 passes cover 512 j-rows; 8 lanes/row -> each wave
        // reads 8 full 128B lines (ideal coalescing) ----
        #pragma unroll
        for (int p = 0; p < 8; ++p) {
            int jr = p * 64 + jhome;
            float4 v = X4[jr * (D / 4) + c * 8 + d4];
            tile[(d4 * 4 + 0) * 513 + jr] = v.x;
            tile[(d4 * 4 + 1) * 513 + jr] = v.y;
            tile[(d4 * 4 + 2) * 513 + jr] = v.z;
            tile[(d4 * 4 + 3) * 513 + jr] = v.w;
        }
        __syncthreads();

        // ---- compute 32 dims for this thread's column j = tid ----
        #pragma unroll
        for (int dd = 0; dd < 32; ++dd) {
            float v = tile[dd * 513 + tid];   // stride-1 across lanes
            int   d = c * 32 + dd;
            float e;
            e = r0[d] - v; a0 += e * e;
            e = r1[d] - v; a1 += e * e;
            e = r2[d] - v; a2 += e * e;
            e = r3[d] - v; a3 += e * e;
        }
        __syncthreads();                      // tile reuse hazard for next chunk
    }

    // a* are exact f32 pair-costs (identical to validated rounds); all
    // j-summation happens in double below.
    double q[8];
    q[0] = (double)a0; q[1] = (double)a1; q[2] = (double)a2; q[3] = (double)a3;
    q[4] = (double)a0 * (double)a0;
    q[5] = (double)a1 * (double)a1;
    q[6] = (double)a2 * (double)a2;
    q[7] = (double)a3 * (double)a3;

    const int wave = tid >> 6;
    const int lane = tid & 63;
    #pragma unroll
    for (int k = 0; k < 8; ++k) {
        double v = wave_reduce_add(q[k]);
        if (lane == 0) red[wave][k] = v;
    }
    __syncthreads();

    if (tid == 0) {
        #pragma unroll
        for (int k = 0; k < 4; ++k) {
            double rsk = 0.0, ssk = 0.0;
            #pragma unroll
            for (int w = 0; w < 8; ++w) { rsk += red[w][k]; ssk += red[w][k + 4]; }
            rs[m * N + i0 + k] = rsk;   // plain stores; visible to K2 at
            ss[m * N + i0 + k] = ssk;   // kernel boundary (proven R3 pattern)
        }
    }
}

// K2: single block combines complete rs/ss (R3's validated finalize).
__global__ __launch_bounds__(512) void gw_finalize(
    const double* __restrict__ rs, const double* __restrict__ ss,
    float* __restrict__ out)
{
    const int i = threadIdx.x;

    const double rs_s = rs[0 * N + i];
    const double rs_t = rs[1 * N + i];
    const double ss_s = ss[0 * N + i];
    const double ss_t = ss[1 * N + i];

    double v = (double)N * (ss_s + ss_t) - 2.0 * rs_s * rs_t;
    v = wave_reduce_add(v);

    __shared__ double sm[8];
    const int wave = i >> 6;
    const int lane = i & 63;
    if (lane == 0) sm[wave] = v;
    __syncthreads();

    if (i == 0) {
        double total = 0.0;
        #pragma unroll
        for (int w = 0; w < 8; ++w) total += sm[w];
        out[0] = (float)(total / ((double)N * (double)N));
    }
}

extern "C" void kernel_launch(void* const* d_in, const int* in_sizes, int n_in,
                              void* d_out, int out_size, void* d_ws, size_t ws_size,
                              hipStream_t stream) {
    const float* src = (const float*)d_in[0];
    const float* tgt = (const float*)d_in[1];
    float* out = (float*)d_out;

    double* rs = (double*)d_ws;             // [2][512]
    double* ss = rs + 2 * N;                // [2][512]

    gw_dist    <<<dim3(256), dim3(512), 0, stream>>>(src, tgt, rs, ss);
    gw_finalize<<<dim3(1),   dim3(512), 0, stream>>>(rs, ss, out);
}